// Round 5
// baseline (167.059 us; speedup 1.0000x reference)
//
#include <hip/hip_runtime.h>

#define D 64
#define DD 4096
#define DDD 262144
#define K 27

typedef _Float16 half8  __attribute__((ext_vector_type(8)));
typedef _Float16 half4v __attribute__((ext_vector_type(4)));
typedef _Float16 half2v __attribute__((ext_vector_type(2)));
typedef float    f32x4  __attribute__((ext_vector_type(4)));
typedef float    f32x2  __attribute__((ext_vector_type(2)));

__device__ inline half2v pk2(float w) {
    return __builtin_bit_cast(half2v, __builtin_amdgcn_cvt_pkrtz(w, w));
}
__device__ inline half2v h2of(half8 v, int d) {
    half2v r; r.x = v[2*d]; r.y = v[2*d+1]; return r;
}

// tile 8x4x2 voxels (x,y,z); halo = tile + 2 each side; packed strides (12 row, 96 plane)
#define HX 12
#define HY 8
#define HZ 6
#define HROW 12
#define HPLN 96
#define HSP  576
#define AS   4608        // HSP*8 halfs: one 8-channel halo array (16B/voxel slots)

#define WSW_CH (14*6*64)       // Wsw: 5376 chunks x 8 f16 = 86016 B
#define KSW_CH (14*64)         // Ksw: 896 chunks x 8 f16 (7 s x 2 halves) = 14336 B
#define KSW_OFF 86016
#define TAPF_OFF (KSW_OFF + KSW_CH*16)   // 100352; 28 x float4 tap-offset table

// compile-time tap displacement in halo-slot units (clamped taps -> tap 0; rows are zero anyway)
__device__ constexpr int dispf(int k) {
    int kk = (k < K) ? k : 0;
    return ((kk / 9) + 1) * HPLN + (((kk / 3) % 3) + 1) * HROW + ((kk % 3) + 1);
}

// ---------------- prep ----------------
__global__ __launch_bounds__(256) void prep_weights(const float* __restrict__ pk,
                                                    const float* __restrict__ kern,
                                                    _Float16* __restrict__ Wsw,
                                                    _Float16* __restrict__ Ksw,
                                                    float* __restrict__ tapf) {
    int t = blockIdx.x * 256 + threadIdx.x;
    if (t < WSW_CH) {
        int lane = t & 63;
        int sm = t >> 6;
        int s = sm / 6, mt = sm - 6 * s;
        int m = mt * 16 + (lane & 15);
        int q = lane >> 4;
        half8 w;
#pragma unroll
        for (int j = 0; j < 8; ++j) {
            int k = 32 * s + 8 * q + j;
            int kt = k >> 4, c = k & 15;
            float wv = (kt < K && m < 81) ? pk[kt * 1296 + c * 81 + m] : 0.0f;
            w[j] = (_Float16)wv;
        }
        *(half8*)(Wsw + t * 8) = w;
    } else if (t < WSW_CH + KSW_CH) {
        int u = t - WSW_CH;
        int lane = u & 63;
        int cch = u >> 6;
        int s = cch >> 1, h = cch & 1;
        int o = lane & 15;
        int tap = 4 * s + (lane >> 4);
        half8 w;
#pragma unroll
        for (int j = 0; j < 8; ++j) {
            int ch = h * 8 + j;
            float wv = (tap < K) ? kern[tap * 256 + ch * 16 + o] : 0.0f;
            w[j] = (_Float16)wv;
        }
        *(half8*)(Ksw + u * 8) = w;
    } else if (t < WSW_CH + KSW_CH + 28) {
        int kt = t - WSW_CH - KSW_CH;
        int ktc = (kt < K) ? kt : K - 1;
        int kd = ktc / 9, kh = (ktc / 3) % 3, kw = ktc % 3;
        f32x4 b;
        b.x = (float)(kd + 1);
        b.y = (float)(kh + 1);
        b.z = (float)(kw + 1);
        b.w = 0.0f;
        *(f32x4*)(tapf + kt * 4) = b;
    }
}

// ---------------- main fused kernel ----------------
__global__ __launch_bounds__(256, 4) void deform_main(
    const float* __restrict__ x,          // [16][64][64][64] fp32
    const _Float16* __restrict__ Wsw,     // phase-1 A-frags
    const _Float16* __restrict__ Ksw,     // phase-2 A-frags (tap-per-group layout)
    const float* __restrict__ tapf,       // 28 x float4 tap coordinate bias
    float* __restrict__ out)              // [16][64][64][64]
{
    __shared__ _Float16 s_h[2 * AS];          // 18432 B: [chan-group][voxel][8]
    __shared__ _Float16 s_off[K * 64 * 4];    // 13824 B: [kt][v][4] (z,y,x,pad) f16
    // total 32256 B -> 5 blocks/CU (LDS-capped)

    const int tid  = threadIdx.x;
    const int lane = tid & 63;
    const int wave = __builtin_amdgcn_readfirstlane(tid >> 6);

    const int bx0 = blockIdx.x * 8;
    const int by0 = blockIdx.y * 4;
    const int bz0 = blockIdx.z * 2;

    // ---- Phase 0: stage halo, fp32 -> f16, split channel-group arrays ----
    for (int i = tid; i < HSP; i += 256) {
        int z = i / HPLN;
        int r = i - z * HPLN;
        int y = r / HROW;
        int xx = r - y * HROW;
        int gz = bz0 - 2 + z, gy = by0 - 2 + y, gx = bx0 - 2 + xx;
        bool in = (unsigned)gz < D && (unsigned)gy < D && (unsigned)gx < D;
        half8 a = {}, b = {};
        if (in) {
            const float* p = x + (gz * DD + gy * D + gx);
#pragma unroll
            for (int c = 0; c < 8; ++c) a[c] = (_Float16)p[c * DDD];
#pragma unroll
            for (int c = 0; c < 8; ++c) b[c] = (_Float16)p[(c + 8) * DDD];
        }
        *(half8*)(s_h + i * 8)      = a;
        *(half8*)(s_h + AS + i * 8) = b;
    }
    __syncthreads();

    // voxel mapping: v = wave*16 + n, n = lane&15
    const int n = lane & 15, q = lane >> 4;
    const int tz = wave >> 1;
    const int ty = 2 * (wave & 1) + (n >> 3);
    const int tx = n & 7;
    const int v = wave * 16 + n;

    // ---- Phase 1: offset conv as f16 MFMA implicit GEMM (M=96,K=448,N=64) ----
    // manual 2-stage pipeline: loads for s+1 issue before the MFMAs of s
    {
        const int qh = q >> 1;
        const int vbase = tz * HPLN + ty * HROW + tx;
        const _Float16* hbase = s_h + (q & 1) * AS;
        f32x4 acc[6] = {};

        half8 bfr, afr[6];
        bfr = *(const half8*)(hbase + (vbase + (qh ? dispf(1) : dispf(0))) * 8);
#pragma unroll
        for (int mt = 0; mt < 6; ++mt)
            afr[mt] = *(const half8*)(Wsw + (mt * 64 + lane) * 8);

#pragma unroll
        for (int s = 0; s < 14; ++s) {
            half8 bnx, anx[6];
            if (s < 13) {
                int disp = qh ? dispf(2 * (s + 1) + 1) : dispf(2 * (s + 1));
                bnx = *(const half8*)(hbase + (vbase + disp) * 8);
#pragma unroll
                for (int mt = 0; mt < 6; ++mt)
                    anx[mt] = *(const half8*)(Wsw + (((s + 1) * 6 + mt) * 64 + lane) * 8);
            }
#pragma unroll
            for (int mt = 0; mt < 6; ++mt)
                acc[mt] = __builtin_amdgcn_mfma_f32_16x16x32_f16(afr[mt], bfr, acc[mt], 0, 0, 0);
            bfr = bnx;
#pragma unroll
            for (int mt = 0; mt < 6; ++mt) afr[mt] = anx[mt];
        }

        // epilogue: write packed s_off[kt][v][c], kt=o/3, c=o%3, o = mt*16 + 4q + r
#pragma unroll
        for (int mt = 0; mt < 6; ++mt)
#pragma unroll
            for (int r = 0; r < 4; ++r) {
                int o = mt * 16 + q * 4 + r;
                if (o < 81) {
                    int kt = (o * 171) >> 9;          // o/3 for o < 96
                    int c = o - kt * 3;
                    s_off[kt * 256 + v * 4 + c] = (_Float16)acc[mt][r];
                }
            }
    }
    __syncthreads();

    // ---- Phase 2: one tap per 16-lane group per iter (kt = 4s+q) ----
    // Branch-free fast path: clamped corner base + wave-ballot rare fixup.
    const float bzf = (float)tz, byf = (float)ty, bxf = (float)tx;
    f32x4 acc2 = {};

    // hoist ALL 7 s_off loads, coords, clamped bases, and bad-lane ballots
    float lzv[7], lyv[7], lxv[7];
    int cb[7];
    unsigned long long badm[7];
#pragma unroll
    for (int s = 0; s < 7; ++s) {
        const int ktr = 4 * s + q;
        const int kt = (ktr < K) ? ktr : K - 1;
        const f32x4 tb = *(const f32x4*)(tapf + kt * 4);
        const half4v off3 = *(const half4v*)(s_off + kt * 256 + v * 4);
        float lz = bzf + tb.x + (float)off3[0];
        float ly = byf + tb.y + (float)off3[1];
        float lx = bxf + tb.z + (float)off3[2];
        lzv[s] = lz; lyv[s] = ly; lxv[s] = lx;
        int hz0 = (int)floorf(lz), hy0 = (int)floorf(ly), hx0 = (int)floorf(lx);
        int hz0c = min(max(hz0, 0), HZ - 2);
        int hy0c = min(max(hy0, 0), HY - 2);
        int hx0c = min(max(hx0, 0), HX - 2);
        bool mis = (hz0 != hz0c) || (hy0 != hy0c) || (hx0 != hx0c);
        badm[s] = __ballot(mis);
        cb[s] = (hz0c * HPLN + hy0c * HROW + hx0c) * 8;
    }

    // rolling prefetch of Ksw A-frags
    half8 alo = *(const half8*)(Ksw + (0 * 64 + lane) * 8);
    half8 ahi = *(const half8*)(Ksw + (1 * 64 + lane) * 8);

#pragma unroll
    for (int s = 0; s < 7; ++s) {
        half8 alo_n, ahi_n;
        if (s < 6) {
            alo_n = *(const half8*)(Ksw + ((2 * s + 2) * 64 + lane) * 8);
            ahi_n = *(const half8*)(Ksw + ((2 * s + 3) * 64 + lane) * 8);
        }

        const float lz = lzv[s], ly = lyv[s], lx = lxv[s];
        const float fz = lz - floorf(lz), fy = ly - floorf(ly), fx = lx - floorf(lx);

        // ---- unconditional clamped corner reads + interp (straight-line) ----
        half2v val2[8];
        {
            const _Float16* cpl = s_h + cb[s];
            float gz1 = 1.0f - fz, gy1 = 1.0f - fy, gx1 = 1.0f - fx;
            float wyx00 = gy1 * gx1, wyx01 = gy1 * fx;
            float wyx10 = fy * gx1,  wyx11 = fy * fx;

            half2v h00a = pk2(gz1 * wyx00);
            half2v h01a = pk2(gz1 * wyx01);
            half2v h10a = pk2(gz1 * wyx10);
            half2v h11a = pk2(gz1 * wyx11);
            half2v h00b = pk2(fz * wyx00);
            half2v h01b = pk2(fz * wyx01);
            half2v h10b = pk2(fz * wyx10);
            half2v h11b = pk2(fz * wyx11);

            half8 l00a = *(const half8*)(cpl);
            half8 l01a = *(const half8*)(cpl + 8);
            half8 l10a = *(const half8*)(cpl + HROW * 8);
            half8 l11a = *(const half8*)(cpl + (HROW + 1) * 8);
            half8 u00a = *(const half8*)(cpl + AS);
            half8 u01a = *(const half8*)(cpl + AS + 8);
            half8 u10a = *(const half8*)(cpl + AS + HROW * 8);
            half8 u11a = *(const half8*)(cpl + AS + (HROW + 1) * 8);
            const _Float16* cpz = cpl + HPLN * 8;
            half8 l00b = *(const half8*)(cpz);
            half8 l01b = *(const half8*)(cpz + 8);
            half8 l10b = *(const half8*)(cpz + HROW * 8);
            half8 l11b = *(const half8*)(cpz + (HROW + 1) * 8);
            half8 u00b = *(const half8*)(cpz + AS);
            half8 u01b = *(const half8*)(cpz + AS + 8);
            half8 u10b = *(const half8*)(cpz + AS + HROW * 8);
            half8 u11b = *(const half8*)(cpz + AS + (HROW + 1) * 8);

#pragma unroll
            for (int d = 0; d < 4; ++d) {
                half2v lo = h00a * h2of(l00a, d);
                half2v hi = h00a * h2of(u00a, d);
                lo += h01a * h2of(l01a, d);
                hi += h01a * h2of(u01a, d);
                lo += h10a * h2of(l10a, d);
                hi += h10a * h2of(u10a, d);
                lo += h11a * h2of(l11a, d);
                hi += h11a * h2of(u11a, d);
                lo += h00b * h2of(l00b, d);
                hi += h00b * h2of(u00b, d);
                lo += h01b * h2of(l01b, d);
                hi += h01b * h2of(u01b, d);
                lo += h10b * h2of(l10b, d);
                hi += h10b * h2of(u10b, d);
                lo += h11b * h2of(l11b, d);
                hi += h11b * h2of(u11b, d);
                val2[d] = lo;
                val2[4 + d] = hi;
            }
        }

        // ---- rare fixup: some lane's 2x2x2 cube left the halo (wave-uniform test) ----
        if (__builtin_expect(badm[s] != 0ull, 0)) {
            int hz0 = (int)floorf(lz), hy0 = (int)floorf(ly), hx0 = (int)floorf(lx);
            bool mis = (hz0 < 0) || (hz0 > HZ - 2) || (hy0 < 0) || (hy0 > HY - 2)
                     || (hx0 < 0) || (hx0 > HX - 2);
            if (mis) {
                int z0 = hz0 + bz0 - 2, y0 = hy0 + by0 - 2, x0 = hx0 + bx0 - 2;
                f32x2 valf[8] = {};
#pragma unroll
                for (int dz = 0; dz < 2; ++dz) {
                    int zi = z0 + dz;
                    float wz = dz ? fz : 1.0f - fz;
#pragma unroll
                    for (int dy = 0; dy < 2; ++dy) {
                        int yi = y0 + dy;
                        float wzy = wz * (dy ? fy : 1.0f - fy);
#pragma unroll
                        for (int dx = 0; dx < 2; ++dx) {
                            int xi = x0 + dx;
                            if ((unsigned)zi < D && (unsigned)yi < D && (unsigned)xi < D) {
                                float w = wzy * (dx ? fx : 1.0f - fx);
                                int base = zi * DD + yi * D + xi;
#pragma unroll
                                for (int d = 0; d < 8; ++d) {
                                    valf[d].x += w * x[(2 * d)     * DDD + base];
                                    valf[d].y += w * x[(2 * d + 1) * DDD + base];
                                }
                            }
                        }
                    }
                }
#pragma unroll
                for (int d = 0; d < 8; ++d) {
                    val2[d].x = (_Float16)valf[d].x;
                    val2[d].y = (_Float16)valf[d].y;
                }
            }
        }

        // registers ARE the B-fragments: blo -> ch 0..7, bhi -> ch 8..15 of tap 4s+q
        half8 blo, bhi;
#pragma unroll
        for (int d = 0; d < 4; ++d) {
            blo[2*d] = val2[d].x;     blo[2*d+1] = val2[d].y;
            bhi[2*d] = val2[4+d].x;   bhi[2*d+1] = val2[4+d].y;
        }
        acc2 = __builtin_amdgcn_mfma_f32_16x16x32_f16(alo, blo, acc2, 0, 0, 0);
        acc2 = __builtin_amdgcn_mfma_f32_16x16x32_f16(ahi, bhi, acc2, 0, 0, 0);
        alo = alo_n;
        ahi = ahi_n;
    }

    // ---- epilogue: C layout col = n (voxel), row = q*4 + r = output channel ----
    const int gz = bz0 + tz, gy = by0 + ty, gx = bx0 + tx;
    const int opos = gz * DD + gy * D + gx;
#pragma unroll
    for (int r = 0; r < 4; ++r) {
        int o = q * 4 + r;
        out[o * DDD + opos] = acc2[r];
    }
}

extern "C" void kernel_launch(void* const* d_in, const int* in_sizes, int n_in,
                              void* d_out, int out_size, void* d_ws, size_t ws_size,
                              hipStream_t stream) {
    const float* x    = (const float*)d_in[0];
    const float* kern = (const float*)d_in[1];
    const float* pk   = (const float*)d_in[2];
    float* out = (float*)d_out;

    _Float16* Wsw = (_Float16*)d_ws;
    _Float16* Ksw = (_Float16*)((char*)d_ws + KSW_OFF);
    float* tapf   = (float*)((char*)d_ws + TAPF_OFF);

    prep_weights<<<25, 256, 0, stream>>>(pk, kern, Wsw, Ksw, tapf);
    deform_main<<<dim3(8, 16, 32), 256, 0, stream>>>(x, Wsw, Ksw, tapf, out);
}

// Round 6
// 143.107 us; speedup vs baseline: 1.1674x; 1.1674x over previous
//
#include <hip/hip_runtime.h>

#define D 64
#define DD 4096
#define DDD 262144
#define K 27

typedef _Float16 half8  __attribute__((ext_vector_type(8)));
typedef _Float16 half4v __attribute__((ext_vector_type(4)));
typedef _Float16 half2v __attribute__((ext_vector_type(2)));
typedef float    f32x4  __attribute__((ext_vector_type(4)));
typedef float    f32x2  __attribute__((ext_vector_type(2)));

__device__ inline half2v pk2(float w) {
    return __builtin_bit_cast(half2v, __builtin_amdgcn_cvt_pkrtz(w, w));
}
__device__ inline half2v h2of(half8 v, int d) {
    half2v r; r.x = v[2*d]; r.y = v[2*d+1]; return r;
}

// tile 8x4x2 voxels (x,y,z); halo = tile + 2 each side; packed strides (12 row, 96 plane)
#define HX 12
#define HY 8
#define HZ 6
#define HROW 12
#define HPLN 96
#define HSP  576
#define AS   4608        // HSP*8 halfs: one 8-channel halo array (16B/voxel slots)

#define WSW_CH (14*6*64)       // Wsw: 5376 chunks x 8 f16 = 86016 B
#define KSW_CH (14*64)         // Ksw: 896 chunks x 8 f16 (7 s x 2 halves) = 14336 B
#define KSW_OFF 86016
#define TAPF_OFF (KSW_OFF + KSW_CH*16)   // 100352; 28 x float4 tap-offset table

// compile-time tap displacement in halo-slot units (clamped taps -> tap 0; rows are zero anyway)
__device__ constexpr int dispf(int k) {
    int kk = (k < K) ? k : 0;
    return ((kk / 9) + 1) * HPLN + (((kk / 3) % 3) + 1) * HROW + ((kk % 3) + 1);
}

// ---------------- prep ----------------
__global__ __launch_bounds__(256) void prep_weights(const float* __restrict__ pk,
                                                    const float* __restrict__ kern,
                                                    _Float16* __restrict__ Wsw,
                                                    _Float16* __restrict__ Ksw,
                                                    float* __restrict__ tapf) {
    int t = blockIdx.x * 256 + threadIdx.x;
    if (t < WSW_CH) {
        int lane = t & 63;
        int sm = t >> 6;
        int s = sm / 6, mt = sm - 6 * s;
        int m = mt * 16 + (lane & 15);
        int q = lane >> 4;
        half8 w;
#pragma unroll
        for (int j = 0; j < 8; ++j) {
            int k = 32 * s + 8 * q + j;
            int kt = k >> 4, c = k & 15;
            float wv = (kt < K && m < 81) ? pk[kt * 1296 + c * 81 + m] : 0.0f;
            w[j] = (_Float16)wv;
        }
        *(half8*)(Wsw + t * 8) = w;
    } else if (t < WSW_CH + KSW_CH) {
        int u = t - WSW_CH;
        int lane = u & 63;
        int cch = u >> 6;
        int s = cch >> 1, h = cch & 1;
        int o = lane & 15;
        int tap = 4 * s + (lane >> 4);
        half8 w;
#pragma unroll
        for (int j = 0; j < 8; ++j) {
            int ch = h * 8 + j;
            float wv = (tap < K) ? kern[tap * 256 + ch * 16 + o] : 0.0f;
            w[j] = (_Float16)wv;
        }
        *(half8*)(Ksw + u * 8) = w;
    } else if (t < WSW_CH + KSW_CH + 28) {
        int kt = t - WSW_CH - KSW_CH;
        int ktc = (kt < K) ? kt : K - 1;
        int kd = ktc / 9, kh = (ktc / 3) % 3, kw = ktc % 3;
        f32x4 b;
        b.x = (float)(kd + 1);
        b.y = (float)(kh + 1);
        b.z = (float)(kw + 1);
        b.w = 0.0f;
        *(f32x4*)(tapf + kt * 4) = b;
    }
}

// ---------------- main fused kernel ----------------
__global__ __launch_bounds__(256, 4) void deform_main(
    const float* __restrict__ x,          // [16][64][64][64] fp32
    const _Float16* __restrict__ Wsw,     // phase-1 A-frags
    const _Float16* __restrict__ Ksw,     // phase-2 A-frags (tap-per-group layout)
    const float* __restrict__ tapf,       // 28 x float4 tap coordinate bias
    float* __restrict__ out)              // [16][64][64][64]
{
    __shared__ _Float16 s_h[2 * AS];          // 18432 B: [chan-group][voxel][8]
    __shared__ _Float16 s_off[K * 64 * 4];    // 13824 B: [kt][v][4] (z,y,x,pad) f16
    // total 32256 B -> 5 blocks/CU (LDS-capped)

    const int tid  = threadIdx.x;
    const int lane = tid & 63;
    const int wave = __builtin_amdgcn_readfirstlane(tid >> 6);

    const int bx0 = blockIdx.x * 8;
    const int by0 = blockIdx.y * 4;
    const int bz0 = blockIdx.z * 2;

    // ---- Phase 0: stage halo, fp32 -> f16, split channel-group arrays ----
    for (int i = tid; i < HSP; i += 256) {
        int z = i / HPLN;
        int r = i - z * HPLN;
        int y = r / HROW;
        int xx = r - y * HROW;
        int gz = bz0 - 2 + z, gy = by0 - 2 + y, gx = bx0 - 2 + xx;
        bool in = (unsigned)gz < D && (unsigned)gy < D && (unsigned)gx < D;
        half8 a = {}, b = {};
        if (in) {
            const float* p = x + (gz * DD + gy * D + gx);
#pragma unroll
            for (int c = 0; c < 8; ++c) a[c] = (_Float16)p[c * DDD];
#pragma unroll
            for (int c = 0; c < 8; ++c) b[c] = (_Float16)p[(c + 8) * DDD];
        }
        *(half8*)(s_h + i * 8)      = a;
        *(half8*)(s_h + AS + i * 8) = b;
    }
    __syncthreads();

    // voxel mapping: v = wave*16 + n, n = lane&15
    const int n = lane & 15, q = lane >> 4;
    const int tz = wave >> 1;
    const int ty = 2 * (wave & 1) + (n >> 3);
    const int tx = n & 7;
    const int v = wave * 16 + n;

    // ---- Phase 1: offset conv as f16 MFMA implicit GEMM (M=96,K=448,N=64) ----
    // manual 2-stage pipeline: loads for s+1 issue before the MFMAs of s
    {
        const int qh = q >> 1;
        const int vbase = tz * HPLN + ty * HROW + tx;
        const _Float16* hbase = s_h + (q & 1) * AS;
        f32x4 acc[6] = {};

        half8 bfr, afr[6];
        bfr = *(const half8*)(hbase + (vbase + (qh ? dispf(1) : dispf(0))) * 8);
#pragma unroll
        for (int mt = 0; mt < 6; ++mt)
            afr[mt] = *(const half8*)(Wsw + (mt * 64 + lane) * 8);

#pragma unroll
        for (int s = 0; s < 14; ++s) {
            half8 bnx, anx[6];
            if (s < 13) {
                int disp = qh ? dispf(2 * (s + 1) + 1) : dispf(2 * (s + 1));
                bnx = *(const half8*)(hbase + (vbase + disp) * 8);
#pragma unroll
                for (int mt = 0; mt < 6; ++mt)
                    anx[mt] = *(const half8*)(Wsw + (((s + 1) * 6 + mt) * 64 + lane) * 8);
            }
#pragma unroll
            for (int mt = 0; mt < 6; ++mt)
                acc[mt] = __builtin_amdgcn_mfma_f32_16x16x32_f16(afr[mt], bfr, acc[mt], 0, 0, 0);
            bfr = bnx;
#pragma unroll
            for (int mt = 0; mt < 6; ++mt) afr[mt] = anx[mt];
        }

        // epilogue: write packed s_off[kt][v][c], kt=o/3, c=o%3, o = mt*16 + 4q + r
#pragma unroll
        for (int mt = 0; mt < 6; ++mt)
#pragma unroll
            for (int r = 0; r < 4; ++r) {
                int o = mt * 16 + q * 4 + r;
                if (o < 81) {
                    int kt = (o * 171) >> 9;          // o/3 for o < 96
                    int c = o - kt * 3;
                    s_off[kt * 256 + v * 4 + c] = (_Float16)acc[mt][r];
                }
            }
    }
    __syncthreads();

    // ---- Phase 2: one tap per 16-lane group per iter (kt = 4s+q) ----
    // Branch-free fast path: clamped corner base; 7-bit wave-uniform fixup mask.
    const float bzf = (float)tz, byf = (float)ty, bxf = (float)tx;
    f32x4 acc2 = {};

    // hoist: s_off loads, coords, clamped bases; compress ballots to 1 bit/s
    float lzv[7], lyv[7], lxv[7];
    int cb[7];
    unsigned badbits = 0;
#pragma unroll
    for (int s = 0; s < 7; ++s) {
        const int ktr = 4 * s + q;
        const int kt = (ktr < K) ? ktr : K - 1;
        const f32x4 tb = *(const f32x4*)(tapf + kt * 4);
        const half4v off3 = *(const half4v*)(s_off + kt * 256 + v * 4);
        float lz = bzf + tb.x + (float)off3[0];
        float ly = byf + tb.y + (float)off3[1];
        float lx = bxf + tb.z + (float)off3[2];
        lzv[s] = lz; lyv[s] = ly; lxv[s] = lx;
        int hz0 = (int)floorf(lz), hy0 = (int)floorf(ly), hx0 = (int)floorf(lx);
        int hz0c = min(max(hz0, 0), HZ - 2);
        int hy0c = min(max(hy0, 0), HY - 2);
        int hx0c = min(max(hx0, 0), HX - 2);
        bool mis = (hz0 != hz0c) || (hy0 != hy0c) || (hx0 != hx0c);
        badbits |= (__ballot(mis) != 0ull) ? (1u << s) : 0u;
        cb[s] = (hz0c * HPLN + hy0c * HROW + hx0c) * 8;
    }

    // rolling prefetch of Ksw A-frags
    half8 alo = *(const half8*)(Ksw + (0 * 64 + lane) * 8);
    half8 ahi = *(const half8*)(Ksw + (1 * 64 + lane) * 8);

#pragma unroll
    for (int s = 0; s < 7; ++s) {
        half8 alo_n, ahi_n;
        if (s < 6) {
            alo_n = *(const half8*)(Ksw + ((2 * s + 2) * 64 + lane) * 8);
            ahi_n = *(const half8*)(Ksw + ((2 * s + 3) * 64 + lane) * 8);
        }

        const float lz = lzv[s], ly = lyv[s], lx = lxv[s];
        const float fz = lz - floorf(lz), fy = ly - floorf(ly), fx = lx - floorf(lx);

        // ---- unconditional clamped corner reads + interp (R4 dz-halved form) ----
        half2v val2[8];
        {
            const _Float16* cpl = s_h + cb[s];
            float gz1 = 1.0f - fz, gy1 = 1.0f - fy, gx1 = 1.0f - fx;
            float wyx00 = gy1 * gx1, wyx01 = gy1 * fx;
            float wyx10 = fy * gx1,  wyx11 = fy * fx;
#pragma unroll
            for (int dz = 0; dz < 2; ++dz) {
                float wz = dz ? fz : gz1;
                const _Float16* cz_ = cpl + dz * (HPLN * 8);
                half2v h00 = pk2(wz * wyx00);
                half2v h01 = pk2(wz * wyx01);
                half2v h10 = pk2(wz * wyx10);
                half2v h11 = pk2(wz * wyx11);
                half8 l00 = *(const half8*)(cz_);
                half8 l01 = *(const half8*)(cz_ + 8);
                half8 l10 = *(const half8*)(cz_ + HROW * 8);
                half8 l11 = *(const half8*)(cz_ + (HROW + 1) * 8);
                half8 u00 = *(const half8*)(cz_ + AS);
                half8 u01 = *(const half8*)(cz_ + AS + 8);
                half8 u10 = *(const half8*)(cz_ + AS + HROW * 8);
                half8 u11 = *(const half8*)(cz_ + AS + (HROW + 1) * 8);
                if (dz == 0) {
#pragma unroll
                    for (int d = 0; d < 4; ++d) {
                        val2[d]      = h00 * h2of(l00, d);
                        val2[4 + d]  = h00 * h2of(u00, d);
                        val2[d]     += h01 * h2of(l01, d);
                        val2[4 + d] += h01 * h2of(u01, d);
                        val2[d]     += h10 * h2of(l10, d);
                        val2[4 + d] += h10 * h2of(u10, d);
                        val2[d]     += h11 * h2of(l11, d);
                        val2[4 + d] += h11 * h2of(u11, d);
                    }
                } else {
#pragma unroll
                    for (int d = 0; d < 4; ++d) {
                        val2[d]     += h00 * h2of(l00, d);
                        val2[4 + d] += h00 * h2of(u00, d);
                        val2[d]     += h01 * h2of(l01, d);
                        val2[4 + d] += h01 * h2of(u01, d);
                        val2[d]     += h10 * h2of(l10, d);
                        val2[4 + d] += h10 * h2of(u10, d);
                        val2[d]     += h11 * h2of(l11, d);
                        val2[4 + d] += h11 * h2of(u11, d);
                    }
                }
            }
        }

        // ---- rare fixup: some lane's 2x2x2 cube left the halo (wave-uniform guard) ----
        if (__builtin_expect((badbits >> s) & 1u, 0)) {
            int hz0 = (int)floorf(lz), hy0 = (int)floorf(ly), hx0 = (int)floorf(lx);
            bool mis = (hz0 < 0) || (hz0 > HZ - 2) || (hy0 < 0) || (hy0 > HY - 2)
                     || (hx0 < 0) || (hx0 > HX - 2);
            if (mis) {
                int z0 = hz0 + bz0 - 2, y0 = hy0 + by0 - 2, x0 = hx0 + bx0 - 2;
                f32x2 valf[8] = {};
#pragma unroll
                for (int dz = 0; dz < 2; ++dz) {
                    int zi = z0 + dz;
                    float wz = dz ? fz : 1.0f - fz;
#pragma unroll
                    for (int dy = 0; dy < 2; ++dy) {
                        int yi = y0 + dy;
                        float wzy = wz * (dy ? fy : 1.0f - fy);
#pragma unroll
                        for (int dx = 0; dx < 2; ++dx) {
                            int xi = x0 + dx;
                            if ((unsigned)zi < D && (unsigned)yi < D && (unsigned)xi < D) {
                                float w = wzy * (dx ? fx : 1.0f - fx);
                                int base = zi * DD + yi * D + xi;
#pragma unroll
                                for (int d = 0; d < 8; ++d) {
                                    valf[d].x += w * x[(2 * d)     * DDD + base];
                                    valf[d].y += w * x[(2 * d + 1) * DDD + base];
                                }
                            }
                        }
                    }
                }
#pragma unroll
                for (int d = 0; d < 8; ++d) {
                    val2[d].x = (_Float16)valf[d].x;
                    val2[d].y = (_Float16)valf[d].y;
                }
            }
        }

        // registers ARE the B-fragments: blo -> ch 0..7, bhi -> ch 8..15 of tap 4s+q
        half8 blo, bhi;
#pragma unroll
        for (int d = 0; d < 4; ++d) {
            blo[2*d] = val2[d].x;     blo[2*d+1] = val2[d].y;
            bhi[2*d] = val2[4+d].x;   bhi[2*d+1] = val2[4+d].y;
        }
        acc2 = __builtin_amdgcn_mfma_f32_16x16x32_f16(alo, blo, acc2, 0, 0, 0);
        acc2 = __builtin_amdgcn_mfma_f32_16x16x32_f16(ahi, bhi, acc2, 0, 0, 0);
        alo = alo_n;
        ahi = ahi_n;
    }

    // ---- epilogue: C layout col = n (voxel), row = q*4 + r = output channel ----
    const int gz = bz0 + tz, gy = by0 + ty, gx = bx0 + tx;
    const int opos = gz * DD + gy * D + gx;
#pragma unroll
    for (int r = 0; r < 4; ++r) {
        int o = q * 4 + r;
        out[o * DDD + opos] = acc2[r];
    }
}

extern "C" void kernel_launch(void* const* d_in, const int* in_sizes, int n_in,
                              void* d_out, int out_size, void* d_ws, size_t ws_size,
                              hipStream_t stream) {
    const float* x    = (const float*)d_in[0];
    const float* kern = (const float*)d_in[1];
    const float* pk   = (const float*)d_in[2];
    float* out = (float*)d_out;

    _Float16* Wsw = (_Float16*)d_ws;
    _Float16* Ksw = (_Float16*)((char*)d_ws + KSW_OFF);
    float* tapf   = (float*)((char*)d_ws + TAPF_OFF);

    prep_weights<<<25, 256, 0, stream>>>(pk, kern, Wsw, Ksw, tapf);
    deform_main<<<dim3(8, 16, 32), 256, 0, stream>>>(x, Wsw, Ksw, tapf, out);
}